// Round 7
// baseline (161.980 us; speedup 1.0000x reference)
//
#include <hip/hip_runtime.h>

#define B_ 16
#define L_ 32
#define O_ 32
#define M_ 256
#define CH_ 544   // L*(P+1)
#define TMOM_BYTES (512 * 256 * 4)

// ---------- cross-lane helpers ----------

__device__ __forceinline__ float rl(float v, int lane) {
  return __int_as_float(__builtin_amdgcn_readlane(__float_as_int(v), lane));
}

__device__ __forceinline__ float sum16_rl(float v) {
  float s = rl(v, 0);
#pragma unroll
  for (int j = 1; j < 16; j++) s += rl(v, j);
  return s;
}

__device__ __forceinline__ float frcp(float x) { return __builtin_amdgcn_rcpf(x); }
__device__ __forceinline__ float frsq(float x) { return __builtin_amdgcn_rsqf(x); }

// ---------- LAPACK helper transcriptions (f32, branchless) ----------
// R2 post-mortem: do NOT touch slartgf's special-case selects (trajectory-
// sensitive). R6 post-mortem: do NOT switch-dispatch the sweep ladders
// (scratch spill, WRITE_SIZE 48->304KB, +17us). The R3 compound-guard
// ladder below is the best known form. R5 ablation: steqr ~48us (65%),
// base ~26us (35%) of the 74us kernel.

__device__ __forceinline__ float slapy2f(float x, float y) {
  float xa = fabsf(x), ya = fabsf(y);
  float w = fmaxf(xa, ya), z = fminf(xa, ya);
  float q = z * frcp(w);
  float res = w * sqrtf(1.f + q * q);
  return (z == 0.f) ? w : res;
}

// LAPACK >= 3.10 slartg convention; single-rsq, branchless.
__device__ __forceinline__ void slartgf(float f, float g, float* c, float* s, float* r) {
  float t = f * f + g * g;
  float inv = frsq(t);
  float d = t * inv;
  float cg = fabsf(f) * inv;
  float rg = copysignf(d, f);
  float sg = g * copysignf(inv, f);
  bool g0 = (g == 0.f), f0 = (f == 0.f);
  *c = g0 ? 1.f : (f0 ? 0.f : cg);
  *s = g0 ? 0.f : (f0 ? copysignf(1.f, g) : sg);
  *r = g0 ? f : (f0 ? fabsf(g) : rg);
}

__device__ __forceinline__ void slaev2f(float a, float b, float c,
                                        float* rt1, float* rt2, float* cs1, float* sn1) {
  float sm = a + c, df = a - c;
  float adf = fabsf(df);
  float tb = b + b;
  float ab = fabsf(tb);
  float acmx, acmn;
  if (fabsf(a) > fabsf(c)) { acmx = a; acmn = c; } else { acmx = c; acmn = a; }
  float rt;
  if (adf > ab) { float q = ab / adf; rt = adf * sqrtf(1.f + q * q); }
  else if (adf < ab) { float q = adf / ab; rt = ab * sqrtf(1.f + q * q); }
  else rt = ab * sqrtf(2.f);
  int sgn1;
  if (sm < 0.f) { *rt1 = 0.5f * (sm - rt); sgn1 = -1; *rt2 = (acmx / *rt1) * acmn - (b / *rt1) * b; }
  else if (sm > 0.f) { *rt1 = 0.5f * (sm + rt); sgn1 = 1; *rt2 = (acmx / *rt1) * acmn - (b / *rt1) * b; }
  else { *rt1 = 0.5f * rt; *rt2 = -0.5f * rt; sgn1 = 1; }
  float cs; int sgn2;
  if (df >= 0.f) { cs = df + rt; sgn2 = 1; } else { cs = df - rt; sgn2 = -1; }
  float acs = fabsf(cs), c1, s1;
  if (acs > ab) { float ct = -tb / cs; s1 = 1.f / sqrtf(1.f + ct * ct); c1 = ct * s1; }
  else if (ab == 0.f) { c1 = 1.f; s1 = 0.f; }
  else { float tn = -cs / tb; c1 = 1.f / sqrtf(1.f + tn * tn); s1 = tn * c1; }
  if (sgn1 == sgn2) { float tn = c1; c1 = -s1; s1 = tn; }
  *cs1 = c1; *sn1 = s1;
}

// ---------- ssteqr replica (R3 baseline form; FP + control verbatim) ----------
__device__ __forceinline__ void steqr16(int lane, float& dreg, float& ereg,
                                        float& dsh, float (&zz)[16]) {
  const float eps = 5.9604645e-08f;
  const float eps2 = eps * eps;
  const float safmin = 1.17549435e-38f;
  int l1 = 0, jtot = 0;
  const int nmaxit = 480;

  while (l1 < 16) {
    if (l1 > 0) { if (lane == l1 - 1) ereg = 0.f; }
    bool co = (lane < 15) &&
              ((ereg == 0.f) ||
               (fabsf(ereg) <= __builtin_amdgcn_sqrtf(fabsf(dreg)) *
                                   __builtin_amdgcn_sqrtf(fabsf(dsh)) * eps));
    unsigned long long bm = __ballot(co) & ~((1ull << l1) - 1ull);
    int m = bm ? (__ffsll(bm) - 1) : 15;
    if (m < 15) { if (lane == m) ereg = 0.f; }
    int l = l1, lend = m;
    l1 = m + 1;
    if (lend == l) continue;
    {
      float dl = rl(dreg, l), dle = rl(dreg, lend);
      if (fabsf(dle) < fabsf(dl)) { int tq = l; l = lend; lend = tq; }
    }

    if (lend > l) {
      // ---- QL ----
      for (;;) {
        bool cj = (lane < 15) && ((ereg * ereg) <= eps2 * fabsf(dreg) * fabsf(dsh) + safmin);
        int mq;
        if (l != lend) {
          unsigned long long bb2 = __ballot(cj) & ((1ull << lend) - 1ull) & ~((1ull << l) - 1ull);
          mq = bb2 ? (__ffsll(bb2) - 1) : lend;
        } else mq = lend;
        if (mq < lend) { if (lane == mq) ereg = 0.f; }
        if (mq == l) { l++; if (l <= lend) continue; break; }
        if (mq == l + 1) {
          float d_l = rl(dreg, l), e_l = rl(ereg, l), d_l1 = rl(dreg, l + 1);
          float rt1, rt2, cc, ss;
          slaev2f(d_l, e_l, d_l1, &rt1, &rt2, &cc, &ss);
#pragma unroll
          for (int k = 0; k < 15; k++) if (k == l) {
            float z1 = zz[k + 1], z0v = zz[k];
            zz[k + 1] = cc * z1 - ss * z0v;
            zz[k] = ss * z1 + cc * z0v;
          }
          if (lane == l) { dreg = rt1; ereg = 0.f; dsh = rt2; }
          if (lane == l + 1) dreg = rt2;
          if (lane == l - 1) dsh = rt1;
          l += 2; if (l <= lend) continue; break;
        }
        if (jtot == nmaxit) break;
        jtot++;
        float d0 = dreg, e0 = ereg;   // pre-sweep snapshots
        float pp = rl(d0, l);
        float e_lv = rl(e0, l);
        float gg = (rl(d0, l + 1) - pp) * 0.5f * frcp(e_lv);
        float rr = slapy2f(gg, 1.f);
        gg = rl(d0, mq) - pp + e_lv * frcp(gg + copysignf(rr, gg));
        float ss_ = 1.f, cc_ = 1.f;
        pp = 0.f;
#pragma unroll
        for (int i = 14; i >= 0; i--) {
          if (i <= mq - 1 && i >= l) {   // wave-uniform guard; i is compile-time
            float e_i = rl(e0, i), d_i = rl(d0, i), d_i1 = rl(d0, i + 1);
            float ff = ss_ * e_i, bb = cc_ * e_i;
            slartgf(gg, ff, &cc_, &ss_, &rr);
            if (i != mq - 1) { if (lane == i + 1) ereg = rr; }
            gg = d_i1 - pp;
            rr = (d_i - gg) * ss_ + 2.f * cc_ * bb;
            pp = ss_ * rr;
            float dnew = gg + pp;
            if (lane == i + 1) dreg = dnew;
            if (lane == i) dsh = dnew;
            gg = cc_ * rr - bb;
            float z1 = zz[i + 1], z0v = zz[i];   // QL (slasr 'B', (c,-s))
            zz[i + 1] = cc_ * z1 + ss_ * z0v;
            zz[i] = -ss_ * z1 + cc_ * z0v;
          }
        }
        float dlv = rl(d0, l) - pp;
        if (lane == l) { dreg = dlv; ereg = gg; }
        if (lane == l - 1) dsh = dlv;
      }
    } else {
      // ---- QR ----
      for (;;) {
        bool cj = (lane < 15) && ((ereg * ereg) <= eps2 * fabsf(dreg) * fabsf(dsh) + safmin);
        int mq;
        if (l != lend) {
          unsigned long long bb2 = __ballot(cj) & ((1ull << l) - 1ull) & ~((1ull << lend) - 1ull);
          mq = bb2 ? (63 - __clzll(bb2) + 1) : lend;
        } else mq = lend;
        if (mq > lend) { if (lane == mq - 1) ereg = 0.f; }
        if (mq == l) { l--; if (l >= lend) continue; break; }
        if (mq == l - 1) {
          float d_lm1 = rl(dreg, l - 1), e_lm1 = rl(ereg, l - 1), d_l = rl(dreg, l);
          float rt1, rt2, cc, ss;
          slaev2f(d_lm1, e_lm1, d_l, &rt1, &rt2, &cc, &ss);
#pragma unroll
          for (int k = 0; k < 15; k++) if (k == l - 1) {
            float z1 = zz[k + 1], z0v = zz[k];
            zz[k + 1] = cc * z1 - ss * z0v;
            zz[k] = ss * z1 + cc * z0v;
          }
          if (lane == l - 1) { dreg = rt1; ereg = 0.f; dsh = rt2; }
          if (lane == l) dreg = rt2;
          if (lane == l - 2) dsh = rt1;
          l -= 2; if (l >= lend) continue; break;
        }
        if (jtot == nmaxit) break;
        jtot++;
        float d0 = dreg, e0 = ereg;
        float pp = rl(d0, l);
        float e_lm1 = rl(e0, l - 1);
        float gg = (rl(d0, l - 1) - pp) * 0.5f * frcp(e_lm1);
        float rr = slapy2f(gg, 1.f);
        gg = rl(d0, mq) - pp + e_lm1 * frcp(gg + copysignf(rr, gg));
        float ss_ = 1.f, cc_ = 1.f;
        pp = 0.f;
#pragma unroll
        for (int i = 0; i <= 14; i++) {
          if (i >= mq && i <= l - 1) {   // wave-uniform guard; i is compile-time
            float e_i = rl(e0, i), d_i = rl(d0, i), d_i1 = rl(d0, i + 1);
            float ff = ss_ * e_i, bb = cc_ * e_i;
            slartgf(gg, ff, &cc_, &ss_, &rr);
            if (i != mq) { if (lane == i - 1) ereg = rr; }
            gg = d_i - pp;
            rr = (d_i1 - gg) * ss_ + 2.f * cc_ * bb;
            pp = ss_ * rr;
            float dnew = gg + pp;
            if (lane == i) dreg = dnew;
            if (lane == i - 1) dsh = dnew;
            gg = cc_ * rr - bb;
            float z1 = zz[i + 1], z0v = zz[i];   // QR (slasr 'F', (c,s))
            zz[i + 1] = cc_ * z1 - ss_ * z0v;
            zz[i] = ss_ * z1 + cc_ * z0v;
          }
        }
        float dlv = rl(d0, l) - pp;
        if (lane == l) dreg = dlv;
        if (lane == l - 1) { ereg = gg; dsh = dlv; }
      }
    }
  }
}

// ---------- Phase 1 body: one weighted pose second-moment tile ----------
// Verbatim R3 moments_kernel body, parameterized on (bl, t).
__device__ __forceinline__ void moments_tile(const float* __restrict__ in,
                                             float* __restrict__ Tmom,
                                             int bl, int t,
                                             float (*ut)[16][68],
                                             float (*red)[16][16]) {
  int b = bl >> 5, l = bl & 31;
  int w = t >> 6, lane = t & 63;
  const float* base = in + (size_t)b * (M_ * CH_);
  const float* row = base + (size_t)(w * 64 + lane) * CH_ + l * 16;
  float4 p0 = *(const float4*)(row + 0);
  float4 p1 = *(const float4*)(row + 4);
  float4 p2 = *(const float4*)(row + 8);
  float4 p3 = *(const float4*)(row + 12);
  float a = row[512 - l * 16 + l];
  float (*u)[68] = ut[w];
  u[0][lane] = a * p0.x;  u[1][lane] = a * p0.y;  u[2][lane] = a * p0.z;  u[3][lane] = a * p0.w;
  u[4][lane] = a * p1.x;  u[5][lane] = a * p1.y;  u[6][lane] = a * p1.z;  u[7][lane] = a * p1.w;
  u[8][lane] = a * p2.x;  u[9][lane] = a * p2.y;  u[10][lane] = a * p2.z; u[11][lane] = a * p2.w;
  u[12][lane] = a * p3.x; u[13][lane] = a * p3.y; u[14][lane] = a * p3.z; u[15][lane] = a * p3.w;
  asm volatile("" ::: "memory");
  int c = lane & 15, r0 = lane >> 4;
  float acc0 = 0.f, acc1 = 0.f, acc2 = 0.f, acc3 = 0.f;
#pragma unroll
  for (int m4 = 0; m4 < 64; m4 += 4) {
    float4 cv = *(const float4*)&u[c][m4];
    float4 a0 = *(const float4*)&u[r0][m4];
    float4 a1 = *(const float4*)&u[r0 + 4][m4];
    float4 a2 = *(const float4*)&u[r0 + 8][m4];
    float4 a3 = *(const float4*)&u[r0 + 12][m4];
    acc0 += a0.x * cv.x + a0.y * cv.y + a0.z * cv.z + a0.w * cv.w;
    acc1 += a1.x * cv.x + a1.y * cv.y + a1.z * cv.z + a1.w * cv.w;
    acc2 += a2.x * cv.x + a2.y * cv.y + a2.z * cv.z + a2.w * cv.w;
    acc3 += a3.x * cv.x + a3.y * cv.y + a3.z * cv.z + a3.w * cv.w;
  }
  red[w][r0][c] = acc0;
  red[w][r0 + 4][c] = acc1;
  red[w][r0 + 8][c] = acc2;
  red[w][r0 + 12][c] = acc3;
  __syncthreads();
  int rr_ = t >> 4, cc_ = t & 15;
  float s = (red[0][rr_][cc_] + red[1][rr_][cc_]) + (red[2][rr_][cc_] + red[3][rr_][cc_]);
  Tmom[bl * 256 + t] = s;
}

// ---------- Phase 2 body: one gram + eigh problem (single wave) ----------
// Verbatim R3 gram_eig_kernel body, parameterized on (bo, lane, LDS set).
__device__ __forceinline__ void gram_eig_one(const float* __restrict__ Tmom,
                                             const float* __restrict__ Wt,
                                             const float* __restrict__ bias,
                                             float* __restrict__ out,
                                             int bo, int lane,
                                             float4* Wall4, float4* Tsh4,
                                             float (*A)[17], float (*Zt)[16]) {
  int b = bo >> 5, o = bo & 31;

  float biasv = bias[o];

  // ---- stage W (single wave: DS in-order, no barrier) ----
  const float4* Wt4 = (const float4*)Wt;
#pragma unroll
  for (int k = 0; k < 2; k++) {
    int idx = lane + 64 * k;
    int l = idx >> 2, part = idx & 3;
    Wall4[idx] = Wt4[(l * 32 + o) * 4 + part];
  }
  asm volatile("" ::: "memory");

  // ---- gram (single-copy T, depth-4 prefetch, barrier-free) ----
  int p = lane >> 2;
  int i_ = p >> 2, k_ = p & 3;
  int i2 = lane & 3;
  float gx = 0.f, gy = 0.f, gz = 0.f, gw = 0.f;
  const float4* T4 = (const float4*)(Tmom + (size_t)(b * 32) * 256);
  const float* WallF = (const float*)Wall4;
  float4 t0 = T4[0 * 64 + lane], t1 = T4[1 * 64 + lane];
  float4 t2 = T4[2 * 64 + lane], t3 = T4[3 * 64 + lane];
  for (int l = 0; l < 32; l++) {
    Tsh4[(lane >> 4) * 18 + (lane & 15)] = t0;
    asm volatile("" ::: "memory");
    t0 = t1; t1 = t2; t2 = t3;
    if (l + 4 < 32) t3 = T4[(l + 4) * 64 + lane];
    float4 wq0 = Wall4[l * 4 + 0], wq1 = Wall4[l * 4 + 1];
    float4 wq2 = Wall4[l * 4 + 2], wq3 = Wall4[l * 4 + 3];
#pragma unroll
    for (int jj = 0; jj < 4; jj++) {
      float4 trow = Tsh4[i_ * 18 + jj * 4 + i2];
      float ux = trow.x * wq0.x + trow.y * wq1.x + trow.z * wq2.x + trow.w * wq3.x;
      float uy = trow.x * wq0.y + trow.y * wq1.y + trow.z * wq2.y + trow.w * wq3.y;
      float uz = trow.x * wq0.z + trow.y * wq1.z + trow.z * wq2.z + trow.w * wq3.z;
      float uw = trow.x * wq0.w + trow.y * wq1.w + trow.z * wq2.w + trow.w * wq3.w;
      float wk = WallF[l * 16 + jj * 4 + k_];
      gx += wk * ux; gy += wk * uy; gz += wk * uz; gw += wk * uw;
    }
    asm volatile("" ::: "memory");
  }
  {
    int q0 = i2 * 4;
    A[p][q0 + 0] = gx; A[p][q0 + 1] = gy; A[p][q0 + 2] = gz; A[p][q0 + 3] = gw;
  }
  asm volatile("" ::: "memory");

  // ---- load A columns into registers: lane c holds a[r] = A[r][c] ----
  int c16 = lane & 15;
  float a[16];
#pragma unroll
  for (int r = 0; r < 16; r++) a[r] = A[r][c16];

  float trace;
  {
    float diag = 0.f;
#pragma unroll
    for (int r = 0; r < 16; r++) if (c16 == r) diag = a[r];
    trace = sum16_rl((lane < 16) ? diag : 0.f);
  }

  // ---- ssytd2 (lower), register-resident ----
  float dreg = 0.f, ereg = 0.f, taureg = 0.f;
  float hv[14];
#pragma unroll
  for (int i = 0; i < 15; i++) {
    float cn = 0.f;
#pragma unroll
    for (int r = i + 2; r < 16; r++) cn += a[r] * a[r];
    float xn2 = rl(cn, i);
    float alpha = rl(a[i + 1], i);
    float taui = 0.f;
    float vc = 0.f;
    if (xn2 == 0.f) {
      if (lane == i) ereg = alpha;
    } else {
      float xnorm = sqrtf(xn2);
      float beta = -copysignf(slapy2f(alpha, xnorm), alpha);
      taui = (beta - alpha) / beta;
      float rs = 1.f / (alpha - beta);
      if (lane == i) ereg = beta;
      vc = (lane == i + 1) ? 1.f : ((lane >= i + 2 && lane < 16) ? a[i] * rs : 0.f);
      float vb[16];
#pragma unroll
      for (int r = i + 1; r < 16; r++) vb[r] = rl(vc, r);
      float acc = 0.f;
#pragma unroll
      for (int r = i + 1; r < 16; r++) acc += a[r] * vb[r];
      float wc = (lane >= i + 1 && lane < 16) ? taui * acc : 0.f;
      float wb[16];
#pragma unroll
      for (int r = i + 1; r < 16; r++) wb[r] = rl(wc, r);
      float dot = 0.f;
#pragma unroll
      for (int r = i + 1; r < 16; r++) dot += vb[r] * wb[r];
      float alph2 = -0.5f * taui * dot;
      wc += alph2 * vc;
#pragma unroll
      for (int r = i + 1; r < 16; r++) wb[r] += alph2 * vb[r];
#pragma unroll
      for (int r = i + 1; r < 16; r++) a[r] -= vb[r] * wc + wb[r] * vc;
    }
    if (i < 14) hv[i] = vc;
    if (lane == i) taureg = taui;
  }
#pragma unroll
  for (int r = 0; r < 16; r++) if (c16 == r) dreg = a[r];
  if (lane >= 16) dreg = 0.f;

  // ---- form Q = H(1)..H(14); lane = column, rows in registers ----
  float z[16];
#pragma unroll
  for (int r = 0; r < 16; r++) z[r] = (lane == r) ? 1.f : 0.f;
#pragma unroll
  for (int i = 13; i >= 0; i--) {
    float taui = rl(taureg, i);
    if (taui != 0.f) {
      float vbq[16];
      float s = 0.f;
#pragma unroll
      for (int r = i + 1; r < 16; r++) { vbq[r] = rl(hv[i], r); s += vbq[r] * z[r]; }
      s *= taui;
#pragma unroll
      for (int r = i + 1; r < 16; r++) z[r] -= vbq[r] * s;
    }
  }
  if (lane < 16) {
    float4* zt4 = (float4*)&Zt[lane][0];      // Zt[col][row]
    zt4[0] = make_float4(z[0], z[1], z[2], z[3]);
    zt4[1] = make_float4(z[4], z[5], z[6], z[7]);
    zt4[2] = make_float4(z[8], z[9], z[10], z[11]);
    zt4[3] = make_float4(z[12], z[13], z[14], z[15]);
  }
  asm volatile("" ::: "memory");

  // ---- transpose handoff: zz[col] = Z[lane][col], register-resident ----
  float zz[16];
#pragma unroll
  for (int k2 = 0; k2 < 16; k2++) zz[k2] = Zt[k2][c16];

  float dsh = __shfl(dreg, (lane + 1) & 63, 64);

  // ---- ssteqr ----
  steqr16(lane, dreg, ereg, dsh, zz);

  // ---- outputs ----
  float mx = rl(dreg, 0);
  int k = 0;
#pragma unroll
  for (int j = 1; j < 16; j++) {
    float dj = rl(dreg, j);
    if (dj > mx) { mx = dj; k = j; }
  }
  float ratio = mx / trace;
  float act = 1.f / (1.f + expf(-(ratio - biasv)));
  float zk = zz[0];
#pragma unroll
  for (int j = 1; j < 16; j++) zk = (k == j) ? zz[j] : zk;
  if (lane < 16) out[512 + bo * 16 + lane] = zk;
  if (lane == 0) out[bo] = act;
}

// ---------- Legacy two-kernel path (fallback if workspace too small) ----------
__global__ __launch_bounds__(256) void moments_kernel(const float* __restrict__ in,
                                                      float* __restrict__ Tmom) {
  __shared__ __align__(16) float ut[4][16][68];
  __shared__ float red[4][16][16];
  moments_tile(in, Tmom, blockIdx.x, threadIdx.x, ut, red);
}

__global__ __launch_bounds__(64) void gram_eig_kernel(const float* __restrict__ Tmom,
                                                      const float* __restrict__ Wt,
                                                      const float* __restrict__ bias,
                                                      float* __restrict__ out) {
  __shared__ __align__(16) float4 Wall4[128];
  __shared__ __align__(16) float4 Tsh4[4 * 18];
  __shared__ float A[16][17];
  __shared__ __align__(16) float Zt[16][16];
  gram_eig_one(Tmom, Wt, bias, out, blockIdx.x, threadIdx.x, Wall4, Tsh4, A, Zt);
}

// ---------- Fused single-launch kernel (atomic spin-sync) ----------
// 256 blocks x 256 threads; block k: phase-1 tiles {2k, 2k+1} (same batch
// b = k>>4), release-add cnt[b]; waves 0/1 acquire-spin until cnt[b]==16,
// then each runs one gram+eigh problem {2k, 2k+1}. 256 blocks <= 256 CUs
// => all blocks resident at ANY occupancy => spin cannot deadlock.
// Both phase bodies are the shared __device__ helpers above (bit-exact).
__global__ __launch_bounds__(256) void fused_kernel(const float* __restrict__ in,
                                                    const float* __restrict__ Wt,
                                                    const float* __restrict__ bias,
                                                    float* __restrict__ out,
                                                    float* __restrict__ Tmom,
                                                    int* __restrict__ cnt) {
  __shared__ __align__(16) float ut[4][16][68];
  __shared__ float red[4][16][16];
  __shared__ __align__(16) float4 Wall4[2][128];
  __shared__ __align__(16) float4 Tsh4[2][4 * 18];
  __shared__ float A[2][16][17];
  __shared__ __align__(16) float Zt[2][16][16];

  int k = blockIdx.x;        // 0..255
  int b = k >> 4;            // batch 0..15 (== (2k)>>5 == (2k+1)>>5)
  int t = threadIdx.x;

  // ---- phase 1: two moment tiles (same batch) ----
  for (int tile = 0; tile < 2; ++tile) {
    moments_tile(in, Tmom, 2 * k + tile, t, ut, red);
    __syncthreads();   // red[] reused by next tile / all stores done before signal
  }

  // ---- producer signal: block's Tmom slice complete ----
  if (t == 0) {
    __threadfence();   // agent-scope release of this block's Tmom stores
    __hip_atomic_fetch_add(&cnt[b], 1, __ATOMIC_RELEASE, __HIP_MEMORY_SCOPE_AGENT);
  }

  // waves 2,3 are done (phase 2 is barrier-free, single-wave per problem)
  if (t >= 128) return;
  int wv = t >> 6, lane = t & 63;

  // ---- consumer spin: wait for all 16 producer blocks of batch b ----
  if (lane == 0) {
    while (__hip_atomic_load(&cnt[b], __ATOMIC_ACQUIRE, __HIP_MEMORY_SCOPE_AGENT) < 16)
      __builtin_amdgcn_s_sleep(2);
  }
  __threadfence();     // order subsequent Tmom reads after the observed signal

  // ---- phase 2: one gram+eigh problem per wave ----
  gram_eig_one(Tmom, Wt, bias, out, 2 * k + wv, lane,
               Wall4[wv], Tsh4[wv], A[wv], Zt[wv]);
}

extern "C" void kernel_launch(void* const* d_in, const int* in_sizes, int n_in,
                              void* d_out, int out_size, void* d_ws, size_t ws_size,
                              hipStream_t stream) {
  const float* in = (const float*)d_in[0];
  const float* w = (const float*)d_in[1];
  const float* bias = (const float*)d_in[2];
  float* out = (float*)d_out;
  float* Tmom = (float*)d_ws;  // 512 * 256 floats = 512 KB scratch

  if (ws_size >= (size_t)TMOM_BYTES + 64) {
    int* cnt = (int*)((char*)d_ws + TMOM_BYTES);   // 16 ints
    hipMemsetAsync(cnt, 0, 64, stream);
    fused_kernel<<<256, 256, 0, stream>>>(in, w, bias, out, Tmom, cnt);
  } else {
    moments_kernel<<<B_ * L_, 256, 0, stream>>>(in, Tmom);
    gram_eig_kernel<<<B_ * O_, 64, 0, stream>>>(Tmom, w, bias, out);
  }
}

// Round 8
// 131.678 us; speedup vs baseline: 1.2301x; 1.2301x over previous
//
#include <hip/hip_runtime.h>

#define B_ 16
#define L_ 32
#define O_ 32
#define M_ 256
#define CH_ 544   // L*(P+1)

// ---------- cross-lane helpers ----------

__device__ __forceinline__ float rl(float v, int lane) {
  return __int_as_float(__builtin_amdgcn_readlane(__float_as_int(v), lane));
}

__device__ __forceinline__ float sum16_rl(float v) {
  float s = rl(v, 0);
#pragma unroll
  for (int j = 1; j < 16; j++) s += rl(v, j);
  return s;
}

__device__ __forceinline__ float frcp(float x) { return __builtin_amdgcn_rcpf(x); }
__device__ __forceinline__ float frsq(float x) { return __builtin_amdgcn_rsqf(x); }

// ---------- LAPACK helper transcriptions (f32, branchless) ----------
// SESSION LEDGER (do not re-litigate):
//  R2: slartgf special-case selects are trajectory-sensitive — touching
//      them changed absmax AND sweep counts. Keep bit-exact.
//  R5: ablation — steqr ~48us (65%), base ~26us (35%) of the 74us kernel.
//  R6: switch-dispatch ladders -> scratch spill (WRITE 48->304KB), +17us.
//  R7: single-launch fusion (spin-sync) -> kernel +31us (phase-1 serialization,
//      producer skew, inline-context codegen drift moved absmax). The ~53us
//      wall-minus-kernel gap is fixed harness overhead, NOT launch gap.
//  This file is the verified-best config: wall 133.1, gram_eig 74.2,
//  absmax 0.0009765625. Byte-exact R3 source.

__device__ __forceinline__ float slapy2f(float x, float y) {
  float xa = fabsf(x), ya = fabsf(y);
  float w = fmaxf(xa, ya), z = fminf(xa, ya);
  float q = z * frcp(w);
  float res = w * sqrtf(1.f + q * q);
  return (z == 0.f) ? w : res;
}

// LAPACK >= 3.10 slartg convention; single-rsq, branchless.
__device__ __forceinline__ void slartgf(float f, float g, float* c, float* s, float* r) {
  float t = f * f + g * g;
  float inv = frsq(t);
  float d = t * inv;
  float cg = fabsf(f) * inv;
  float rg = copysignf(d, f);
  float sg = g * copysignf(inv, f);
  bool g0 = (g == 0.f), f0 = (f == 0.f);
  *c = g0 ? 1.f : (f0 ? 0.f : cg);
  *s = g0 ? 0.f : (f0 ? copysignf(1.f, g) : sg);
  *r = g0 ? f : (f0 ? fabsf(g) : rg);
}

__device__ __forceinline__ void slaev2f(float a, float b, float c,
                                        float* rt1, float* rt2, float* cs1, float* sn1) {
  float sm = a + c, df = a - c;
  float adf = fabsf(df);
  float tb = b + b;
  float ab = fabsf(tb);
  float acmx, acmn;
  if (fabsf(a) > fabsf(c)) { acmx = a; acmn = c; } else { acmx = c; acmn = a; }
  float rt;
  if (adf > ab) { float q = ab / adf; rt = adf * sqrtf(1.f + q * q); }
  else if (adf < ab) { float q = adf / ab; rt = ab * sqrtf(1.f + q * q); }
  else rt = ab * sqrtf(2.f);
  int sgn1;
  if (sm < 0.f) { *rt1 = 0.5f * (sm - rt); sgn1 = -1; *rt2 = (acmx / *rt1) * acmn - (b / *rt1) * b; }
  else if (sm > 0.f) { *rt1 = 0.5f * (sm + rt); sgn1 = 1; *rt2 = (acmx / *rt1) * acmn - (b / *rt1) * b; }
  else { *rt1 = 0.5f * rt; *rt2 = -0.5f * rt; sgn1 = 1; }
  float cs; int sgn2;
  if (df >= 0.f) { cs = df + rt; sgn2 = 1; } else { cs = df - rt; sgn2 = -1; }
  float acs = fabsf(cs), c1, s1;
  if (acs > ab) { float ct = -tb / cs; s1 = 1.f / sqrtf(1.f + ct * ct); c1 = ct * s1; }
  else if (ab == 0.f) { c1 = 1.f; s1 = 0.f; }
  else { float tn = -cs / tb; c1 = 1.f / sqrtf(1.f + tn * tn); s1 = tn * c1; }
  if (sgn1 == sgn2) { float tn = c1; c1 = -s1; s1 = tn; }
  *cs1 = c1; *sn1 = s1;
}

// ---------- Kernel 1: weighted pose second moments (single reduced copy) ----------
__global__ __launch_bounds__(256) void moments_kernel(const float* __restrict__ in,
                                                      float* __restrict__ Tmom) {
  int bl = blockIdx.x;
  int b = bl >> 5, l = bl & 31;
  int t = threadIdx.x;
  int w = t >> 6, lane = t & 63;
  __shared__ __align__(16) float ut[4][16][68];
  __shared__ float red[4][16][16];
  const float* base = in + (size_t)b * (M_ * CH_);
  const float* row = base + (size_t)(w * 64 + lane) * CH_ + l * 16;
  float4 p0 = *(const float4*)(row + 0);
  float4 p1 = *(const float4*)(row + 4);
  float4 p2 = *(const float4*)(row + 8);
  float4 p3 = *(const float4*)(row + 12);
  float a = row[512 - l * 16 + l];
  float (*u)[68] = ut[w];
  u[0][lane] = a * p0.x;  u[1][lane] = a * p0.y;  u[2][lane] = a * p0.z;  u[3][lane] = a * p0.w;
  u[4][lane] = a * p1.x;  u[5][lane] = a * p1.y;  u[6][lane] = a * p1.z;  u[7][lane] = a * p1.w;
  u[8][lane] = a * p2.x;  u[9][lane] = a * p2.y;  u[10][lane] = a * p2.z; u[11][lane] = a * p2.w;
  u[12][lane] = a * p3.x; u[13][lane] = a * p3.y; u[14][lane] = a * p3.z; u[15][lane] = a * p3.w;
  asm volatile("" ::: "memory");
  int c = lane & 15, r0 = lane >> 4;
  float acc0 = 0.f, acc1 = 0.f, acc2 = 0.f, acc3 = 0.f;
#pragma unroll
  for (int m4 = 0; m4 < 64; m4 += 4) {
    float4 cv = *(const float4*)&u[c][m4];
    float4 a0 = *(const float4*)&u[r0][m4];
    float4 a1 = *(const float4*)&u[r0 + 4][m4];
    float4 a2 = *(const float4*)&u[r0 + 8][m4];
    float4 a3 = *(const float4*)&u[r0 + 12][m4];
    acc0 += a0.x * cv.x + a0.y * cv.y + a0.z * cv.z + a0.w * cv.w;
    acc1 += a1.x * cv.x + a1.y * cv.y + a1.z * cv.z + a1.w * cv.w;
    acc2 += a2.x * cv.x + a2.y * cv.y + a2.z * cv.z + a2.w * cv.w;
    acc3 += a3.x * cv.x + a3.y * cv.y + a3.z * cv.z + a3.w * cv.w;
  }
  red[w][r0][c] = acc0;
  red[w][r0 + 4][c] = acc1;
  red[w][r0 + 8][c] = acc2;
  red[w][r0 + 12][c] = acc3;
  __syncthreads();
  int rr_ = t >> 4, cc_ = t & 15;
  float s = (red[0][rr_][cc_] + red[1][rr_][cc_]) + (red[2][rr_][cc_] + red[3][rr_][cc_]);
  Tmom[bl * 256 + t] = s;
}

// ---------- Kernel 2: gram + register-resident LAPACK-replica eigh ----------
__global__ __launch_bounds__(64) void gram_eig_kernel(const float* __restrict__ Tmom,
                                                      const float* __restrict__ Wt,
                                                      const float* __restrict__ bias,
                                                      float* __restrict__ out) {
  int bo = blockIdx.x;
  int b = bo >> 5, o = bo & 31;
  int lane = threadIdx.x;

  __shared__ __align__(16) float4 Wall4[128];
  __shared__ __align__(16) float4 Tsh4[4 * 18];
  __shared__ float A[16][17];
  __shared__ __align__(16) float Zt[16][16];

  float biasv = bias[o];

  // ---- stage W (single wave: DS in-order, no barrier) ----
  const float4* Wt4 = (const float4*)Wt;
#pragma unroll
  for (int k = 0; k < 2; k++) {
    int idx = lane + 64 * k;
    int l = idx >> 2, part = idx & 3;
    Wall4[idx] = Wt4[(l * 32 + o) * 4 + part];
  }
  asm volatile("" ::: "memory");

  // ---- gram (single-copy T, depth-4 prefetch, barrier-free) ----
  int p = lane >> 2;
  int i_ = p >> 2, k_ = p & 3;
  int i2 = lane & 3;
  float gx = 0.f, gy = 0.f, gz = 0.f, gw = 0.f;
  const float4* T4 = (const float4*)(Tmom + (size_t)(b * 32) * 256);
  const float* WallF = (const float*)Wall4;
  float4 t0 = T4[0 * 64 + lane], t1 = T4[1 * 64 + lane];
  float4 t2 = T4[2 * 64 + lane], t3 = T4[3 * 64 + lane];
  for (int l = 0; l < 32; l++) {
    Tsh4[(lane >> 4) * 18 + (lane & 15)] = t0;
    asm volatile("" ::: "memory");
    t0 = t1; t1 = t2; t2 = t3;
    if (l + 4 < 32) t3 = T4[(l + 4) * 64 + lane];
    float4 wq0 = Wall4[l * 4 + 0], wq1 = Wall4[l * 4 + 1];
    float4 wq2 = Wall4[l * 4 + 2], wq3 = Wall4[l * 4 + 3];
#pragma unroll
    for (int jj = 0; jj < 4; jj++) {
      float4 trow = Tsh4[i_ * 18 + jj * 4 + i2];
      float ux = trow.x * wq0.x + trow.y * wq1.x + trow.z * wq2.x + trow.w * wq3.x;
      float uy = trow.x * wq0.y + trow.y * wq1.y + trow.z * wq2.y + trow.w * wq3.y;
      float uz = trow.x * wq0.z + trow.y * wq1.z + trow.z * wq2.z + trow.w * wq3.z;
      float uw = trow.x * wq0.w + trow.y * wq1.w + trow.z * wq2.w + trow.w * wq3.w;
      float wk = WallF[l * 16 + jj * 4 + k_];
      gx += wk * ux; gy += wk * uy; gz += wk * uz; gw += wk * uw;
    }
    asm volatile("" ::: "memory");
  }
  {
    int q0 = i2 * 4;
    A[p][q0 + 0] = gx; A[p][q0 + 1] = gy; A[p][q0 + 2] = gz; A[p][q0 + 3] = gw;
  }
  asm volatile("" ::: "memory");

  // ---- load A columns into registers: lane c holds a[r] = A[r][c] ----
  int c16 = lane & 15;
  float a[16];
#pragma unroll
  for (int r = 0; r < 16; r++) a[r] = A[r][c16];

  float trace;
  {
    float diag = 0.f;
#pragma unroll
    for (int r = 0; r < 16; r++) if (c16 == r) diag = a[r];
    trace = sum16_rl((lane < 16) ? diag : 0.f);
  }

  // ---- ssytd2 (lower), register-resident ----
  float dreg = 0.f, ereg = 0.f, taureg = 0.f;
  float hv[14];
#pragma unroll
  for (int i = 0; i < 15; i++) {
    float cn = 0.f;
#pragma unroll
    for (int r = i + 2; r < 16; r++) cn += a[r] * a[r];
    float xn2 = rl(cn, i);
    float alpha = rl(a[i + 1], i);
    float taui = 0.f;
    float vc = 0.f;
    if (xn2 == 0.f) {
      if (lane == i) ereg = alpha;
    } else {
      float xnorm = sqrtf(xn2);
      float beta = -copysignf(slapy2f(alpha, xnorm), alpha);
      taui = (beta - alpha) / beta;
      float rs = 1.f / (alpha - beta);
      if (lane == i) ereg = beta;
      vc = (lane == i + 1) ? 1.f : ((lane >= i + 2 && lane < 16) ? a[i] * rs : 0.f);
      float vb[16];
#pragma unroll
      for (int r = i + 1; r < 16; r++) vb[r] = rl(vc, r);
      float acc = 0.f;
#pragma unroll
      for (int r = i + 1; r < 16; r++) acc += a[r] * vb[r];
      float wc = (lane >= i + 1 && lane < 16) ? taui * acc : 0.f;
      float wb[16];
#pragma unroll
      for (int r = i + 1; r < 16; r++) wb[r] = rl(wc, r);
      float dot = 0.f;
#pragma unroll
      for (int r = i + 1; r < 16; r++) dot += vb[r] * wb[r];
      float alph2 = -0.5f * taui * dot;
      wc += alph2 * vc;
#pragma unroll
      for (int r = i + 1; r < 16; r++) wb[r] += alph2 * vb[r];
#pragma unroll
      for (int r = i + 1; r < 16; r++) a[r] -= vb[r] * wc + wb[r] * vc;
    }
    if (i < 14) hv[i] = vc;
    if (lane == i) taureg = taui;
  }
#pragma unroll
  for (int r = 0; r < 16; r++) if (c16 == r) dreg = a[r];
  if (lane >= 16) dreg = 0.f;

  // ---- form Q = H(1)..H(14); lane = column, rows in registers ----
  float z[16];
#pragma unroll
  for (int r = 0; r < 16; r++) z[r] = (lane == r) ? 1.f : 0.f;
#pragma unroll
  for (int i = 13; i >= 0; i--) {
    float taui = rl(taureg, i);
    if (taui != 0.f) {
      float vbq[16];
      float s = 0.f;
#pragma unroll
      for (int r = i + 1; r < 16; r++) { vbq[r] = rl(hv[i], r); s += vbq[r] * z[r]; }
      s *= taui;
#pragma unroll
      for (int r = i + 1; r < 16; r++) z[r] -= vbq[r] * s;
    }
  }
  if (lane < 16) {
    float4* zt4 = (float4*)&Zt[lane][0];      // Zt[col][row]
    zt4[0] = make_float4(z[0], z[1], z[2], z[3]);
    zt4[1] = make_float4(z[4], z[5], z[6], z[7]);
    zt4[2] = make_float4(z[8], z[9], z[10], z[11]);
    zt4[3] = make_float4(z[12], z[13], z[14], z[15]);
  }
  asm volatile("" ::: "memory");

  // ---- transpose handoff: zz[col] = Z[lane][col], register-resident ----
  float zz[16];
#pragma unroll
  for (int k2 = 0; k2 < 16; k2++) zz[k2] = Zt[k2][c16];

  // ---- ssteqr; d,e lane-resident; Z in registers; sweeps unrolled ----
  const float eps = 5.9604645e-08f;
  const float eps2 = eps * eps;
  const float safmin = 1.17549435e-38f;
  int l1 = 0, jtot = 0;
  const int nmaxit = 480;
  float dsh = __shfl(dreg, (lane + 1) & 63, 64);

  while (l1 < 16) {
    if (l1 > 0) { if (lane == l1 - 1) ereg = 0.f; }
    bool co = (lane < 15) &&
              ((ereg == 0.f) ||
               (fabsf(ereg) <= __builtin_amdgcn_sqrtf(fabsf(dreg)) *
                                   __builtin_amdgcn_sqrtf(fabsf(dsh)) * eps));
    unsigned long long bm = __ballot(co) & ~((1ull << l1) - 1ull);
    int m = bm ? (__ffsll(bm) - 1) : 15;
    if (m < 15) { if (lane == m) ereg = 0.f; }
    int l = l1, lend = m;
    l1 = m + 1;
    if (lend == l) continue;
    {
      float dl = rl(dreg, l), dle = rl(dreg, lend);
      if (fabsf(dle) < fabsf(dl)) { int tq = l; l = lend; lend = tq; }
    }

    if (lend > l) {
      // ---- QL ----
      for (;;) {
        bool cj = (lane < 15) && ((ereg * ereg) <= eps2 * fabsf(dreg) * fabsf(dsh) + safmin);
        int mq;
        if (l != lend) {
          unsigned long long bb2 = __ballot(cj) & ((1ull << lend) - 1ull) & ~((1ull << l) - 1ull);
          mq = bb2 ? (__ffsll(bb2) - 1) : lend;
        } else mq = lend;
        if (mq < lend) { if (lane == mq) ereg = 0.f; }
        if (mq == l) { l++; if (l <= lend) continue; break; }
        if (mq == l + 1) {
          float d_l = rl(dreg, l), e_l = rl(ereg, l), d_l1 = rl(dreg, l + 1);
          float rt1, rt2, cc, ss;
          slaev2f(d_l, e_l, d_l1, &rt1, &rt2, &cc, &ss);
#pragma unroll
          for (int k = 0; k < 15; k++) if (k == l) {
            float z1 = zz[k + 1], z0v = zz[k];
            zz[k + 1] = cc * z1 - ss * z0v;
            zz[k] = ss * z1 + cc * z0v;
          }
          if (lane == l) { dreg = rt1; ereg = 0.f; dsh = rt2; }
          if (lane == l + 1) dreg = rt2;
          if (lane == l - 1) dsh = rt1;
          l += 2; if (l <= lend) continue; break;
        }
        if (jtot == nmaxit) break;
        jtot++;
        float d0 = dreg, e0 = ereg;   // pre-sweep snapshots
        float pp = rl(d0, l);
        float e_lv = rl(e0, l);
        float gg = (rl(d0, l + 1) - pp) * 0.5f * frcp(e_lv);
        float rr = slapy2f(gg, 1.f);
        gg = rl(d0, mq) - pp + e_lv * frcp(gg + copysignf(rr, gg));
        float ss_ = 1.f, cc_ = 1.f;
        pp = 0.f;
#pragma unroll
        for (int i = 14; i >= 0; i--) {
          if (i <= mq - 1 && i >= l) {   // wave-uniform guard; i is compile-time
            float e_i = rl(e0, i), d_i = rl(d0, i), d_i1 = rl(d0, i + 1);
            float ff = ss_ * e_i, bb = cc_ * e_i;
            slartgf(gg, ff, &cc_, &ss_, &rr);
            if (i != mq - 1) { if (lane == i + 1) ereg = rr; }
            gg = d_i1 - pp;
            rr = (d_i - gg) * ss_ + 2.f * cc_ * bb;
            pp = ss_ * rr;
            float dnew = gg + pp;
            if (lane == i + 1) dreg = dnew;
            if (lane == i) dsh = dnew;
            gg = cc_ * rr - bb;
            float z1 = zz[i + 1], z0v = zz[i];   // QL (slasr 'B', (c,-s))
            zz[i + 1] = cc_ * z1 + ss_ * z0v;
            zz[i] = -ss_ * z1 + cc_ * z0v;
          }
        }
        float dlv = rl(d0, l) - pp;
        if (lane == l) { dreg = dlv; ereg = gg; }
        if (lane == l - 1) dsh = dlv;
      }
    } else {
      // ---- QR ----
      for (;;) {
        bool cj = (lane < 15) && ((ereg * ereg) <= eps2 * fabsf(dreg) * fabsf(dsh) + safmin);
        int mq;
        if (l != lend) {
          unsigned long long bb2 = __ballot(cj) & ((1ull << l) - 1ull) & ~((1ull << lend) - 1ull);
          mq = bb2 ? (63 - __clzll(bb2) + 1) : lend;
        } else mq = lend;
        if (mq > lend) { if (lane == mq - 1) ereg = 0.f; }
        if (mq == l) { l--; if (l >= lend) continue; break; }
        if (mq == l - 1) {
          float d_lm1 = rl(dreg, l - 1), e_lm1 = rl(ereg, l - 1), d_l = rl(dreg, l);
          float rt1, rt2, cc, ss;
          slaev2f(d_lm1, e_lm1, d_l, &rt1, &rt2, &cc, &ss);
#pragma unroll
          for (int k = 0; k < 15; k++) if (k == l - 1) {
            float z1 = zz[k + 1], z0v = zz[k];
            zz[k + 1] = cc * z1 - ss * z0v;
            zz[k] = ss * z1 + cc * z0v;
          }
          if (lane == l - 1) { dreg = rt1; ereg = 0.f; dsh = rt2; }
          if (lane == l) dreg = rt2;
          if (lane == l - 2) dsh = rt1;
          l -= 2; if (l >= lend) continue; break;
        }
        if (jtot == nmaxit) break;
        jtot++;
        float d0 = dreg, e0 = ereg;
        float pp = rl(d0, l);
        float e_lm1 = rl(e0, l - 1);
        float gg = (rl(d0, l - 1) - pp) * 0.5f * frcp(e_lm1);
        float rr = slapy2f(gg, 1.f);
        gg = rl(d0, mq) - pp + e_lm1 * frcp(gg + copysignf(rr, gg));
        float ss_ = 1.f, cc_ = 1.f;
        pp = 0.f;
#pragma unroll
        for (int i = 0; i <= 14; i++) {
          if (i >= mq && i <= l - 1) {   // wave-uniform guard; i is compile-time
            float e_i = rl(e0, i), d_i = rl(d0, i), d_i1 = rl(d0, i + 1);
            float ff = ss_ * e_i, bb = cc_ * e_i;
            slartgf(gg, ff, &cc_, &ss_, &rr);
            if (i != mq) { if (lane == i - 1) ereg = rr; }
            gg = d_i - pp;
            rr = (d_i1 - gg) * ss_ + 2.f * cc_ * bb;
            pp = ss_ * rr;
            float dnew = gg + pp;
            if (lane == i) dreg = dnew;
            if (lane == i - 1) dsh = dnew;
            gg = cc_ * rr - bb;
            float z1 = zz[i + 1], z0v = zz[i];   // QR (slasr 'F', (c,s))
            zz[i + 1] = cc_ * z1 - ss_ * z0v;
            zz[i] = ss_ * z1 + cc_ * z0v;
          }
        }
        float dlv = rl(d0, l) - pp;
        if (lane == l) dreg = dlv;
        if (lane == l - 1) { ereg = gg; dsh = dlv; }
      }
    }
  }

  // ---- outputs ----
  float mx = rl(dreg, 0);
  int k = 0;
#pragma unroll
  for (int j = 1; j < 16; j++) {
    float dj = rl(dreg, j);
    if (dj > mx) { mx = dj; k = j; }
  }
  float ratio = mx / trace;
  float act = 1.f / (1.f + expf(-(ratio - biasv)));
  float zk = zz[0];
#pragma unroll
  for (int j = 1; j < 16; j++) zk = (k == j) ? zz[j] : zk;
  if (lane < 16) out[512 + bo * 16 + lane] = zk;
  if (lane == 0) out[bo] = act;
}

extern "C" void kernel_launch(void* const* d_in, const int* in_sizes, int n_in,
                              void* d_out, int out_size, void* d_ws, size_t ws_size,
                              hipStream_t stream) {
  const float* in = (const float*)d_in[0];
  const float* w = (const float*)d_in[1];
  const float* bias = (const float*)d_in[2];
  float* out = (float*)d_out;
  float* Tmom = (float*)d_ws;  // 512 * 256 floats = 512 KB scratch

  moments_kernel<<<B_ * L_, 256, 0, stream>>>(in, Tmom);
  gram_eig_kernel<<<B_ * O_, 64, 0, stream>>>(Tmom, w, bias, out);
}